// Round 5
// baseline (142.893 us; speedup 1.0000x reference)
//
#include <hip/hip_runtime.h>
#include <stdint.h>

// FP4 quant-dequant, faithful to the JAX reference in float32 arithmetic.
// v7: verified v2 numerics verbatim (exact per-element __fdiv_rn + 10-rung
// ladder -- v6 proved threshold-compare flips ~5 elements/run at 0.25*ds
// each, 4x over threshold; the divide is NOT removable). Structural change
// only: k_reduce launch eliminated via uint-ordered atomicMin/Max on a
// 2-word header (scales>0 so float order == uint order), initialized by two
// 4-byte stream-ordered memsets. k_quant reads the 8B header per thread
// (scalar load) -- avoids v5's 134MB of redundant per-WG partial re-reads.
// VALU model corrected: CU = 4xSIMD-32 = 128 lanes/cyc -> quant VALU ~9.5us,
// below its memory time; both kernels are memory/launch-bound.

#define BLK 64
#define WG 256
#define FLT_BIG 3.402823466e+38f

// Branchless insert of `a` into descending-sorted top-5 register array.
__device__ __forceinline__ void ins5(float (&t)[5], float a) {
#pragma unroll
    for (int k = 0; k < 4; ++k) {
        float m = fmaxf(t[k], a);
        a = fminf(t[k], a);
        t[k] = m;
    }
    t[4] = fmaxf(t[4], a);
}

// JAX f32 quantile: q = 0.95f*63.0f; result = v59*lw + v60*hw
__device__ __forceinline__ float quantile5(const float (&A)[5]) {
    const float qs = 0.95f * 63.0f;      // 59.849998474121094f
    const float hw = qs - 59.0f;
    const float lw = 60.0f - qs;
    // A[3] = 4th largest = sorted v[60]; A[4] = 5th largest = v[59]
    float s = __fadd_rn(__fmul_rn(A[4], lw), __fmul_rn(A[3], hw));
    return fmaxf(s, 1e-8f);
}

// Nearest FP4 level via boundary ladder on the EXACT quotient fl(x/s).
// Midpoints and partial sums are exact dyadics; ties at exact midpoints go
// to the lower-index (more negative) level, matching argmin-first-index.
__device__ __forceinline__ float qlevel(float xn) {
    float bv = -3.0f;
    bv += (xn > -2.5f)   ? 1.0f  : 0.0f;
    bv += (xn > -1.75f)  ? 0.5f  : 0.0f;
    bv += (xn > -1.25f)  ? 0.5f  : 0.0f;
    bv += (xn > -0.875f) ? 0.25f : 0.0f;
    bv += (xn > -0.375f) ? 0.75f : 0.0f;
    bv += (xn > 0.375f)  ? 0.75f : 0.0f;
    bv += (xn > 0.875f)  ? 0.25f : 0.0f;
    bv += (xn > 1.25f)   ? 0.5f  : 0.0f;
    bv += (xn > 1.75f)   ? 0.5f  : 0.0f;
    bv += (xn > 2.5f)    ? 1.0f  : 0.0f;
    return bv;
}

// ---------------- Kernel 1: per-block scales + header atomics ----------------
// One thread = one 64-element block (16 independent float4 loads). Verified
// numerics (exact order-independent top-5; JAX-f32 quantile interp).
// hdr[0]/hdr[1] hold global scale min/max as uint-ordered float bits;
// initialized to 0xFFFFFFFF / 0x00000000 by host-side memsetAsync.
__global__ __launch_bounds__(WG) void k_scales(const float* __restrict__ x,
                                               int n, int nblocks,
                                               float* __restrict__ scales,
                                               unsigned int* __restrict__ hdr) {
    const int b = blockIdx.x * WG + threadIdx.x;
    const bool valid = (b < nblocks);

    float s = 0.0f;
    if (valid) {
        float4 v[16];
        const int base = b * BLK;
        if (base + BLK <= n) {
            const float4* x4 = reinterpret_cast<const float4*>(x + base);
#pragma unroll
            for (int j = 0; j < 16; ++j) v[j] = x4[j];
        } else {
            for (int j = 0; j < 16; ++j) {
                float tmp[4];
                for (int k = 0; k < 4; ++k) {
                    int idx = base + j * 4 + k;
                    tmp[k] = (idx < n) ? x[idx] : 0.0f;  // reference zero-pads
                }
                v[j] = make_float4(tmp[0], tmp[1], tmp[2], tmp[3]);
            }
        }
        // Two insertion chains for ILP; abs>=0 so 0-init is safe.
        float A[5] = {0.f, 0.f, 0.f, 0.f, 0.f};
        float B[5] = {0.f, 0.f, 0.f, 0.f, 0.f};
#pragma unroll
        for (int j = 0; j < 16; j += 2) {
            ins5(A, fabsf(v[j].x));     ins5(B, fabsf(v[j + 1].x));
            ins5(A, fabsf(v[j].y));     ins5(B, fabsf(v[j + 1].y));
            ins5(A, fabsf(v[j].z));     ins5(B, fabsf(v[j + 1].z));
            ins5(A, fabsf(v[j].w));     ins5(B, fabsf(v[j + 1].w));
        }
#pragma unroll
        for (int k = 0; k < 5; ++k) ins5(A, B[k]);
        s = quantile5(A);
        scales[b] = s;
    }

    // Per-WG scale min/max, then ONE atomicMin + ONE atomicMax per WG.
    // s >= 1e-8 > 0, so float ordering == uint ordering on the bit pattern.
    float mn = valid ? s : FLT_BIG;
    float mx = valid ? s : 0.0f;
#pragma unroll
    for (int off = 32; off > 0; off >>= 1) {
        mn = fminf(mn, __shfl_xor(mn, off, 64));
        mx = fmaxf(mx, __shfl_xor(mx, off, 64));
    }
    __shared__ float smn[4], smx[4];
    const int lane = threadIdx.x & 63, w = threadIdx.x >> 6;
    if (lane == 0) { smn[w] = mn; smx[w] = mx; }
    __syncthreads();
    if (threadIdx.x == 0) {
        float fmn = smn[0], fmx = smx[0];
#pragma unroll
        for (int i = 1; i < 4; ++i) { fmn = fminf(fmn, smn[i]); fmx = fmaxf(fmx, smx[i]); }
        atomicMin(&hdr[0], __float_as_uint(fmn));
        atomicMax(&hdr[1], __float_as_uint(fmx));
    }
}

// ------------- Kernel 2: quantize (v2-verbatim math, header read) -------------
__global__ __launch_bounds__(WG) void k_quant(const float* __restrict__ x,
                                              const float* __restrict__ scales,
                                              const unsigned int* __restrict__ hdr,
                                              int n,
                                              float* __restrict__ out) {
    const int t = blockIdx.x * WG + threadIdx.x;
    const int i = t * 4;
    if (i >= n) return;

    const float smin = __uint_as_float(hdr[0]);
    const float smax = __uint_as_float(hdr[1]);
    const int b = i >> 6;               // 4-aligned group never crosses a block
    const float s = scales[b];

    // Double-quantization of the scale (exact path).
    float ds;
    if (smax > smin) {
        const float ss = __fdiv_rn(__fsub_rn(smax, smin), 255.0f);
        float q = rintf(__fdiv_rn(__fsub_rn(s, smin), ss));   // round half-even
        q = fminf(fmaxf(q, 0.0f), 255.0f);                    // clip AFTER round
        ds = __fmul_rn(q, ss);
    } else {
        ds = 0.0f;   // q=0, scale_scale=1 -> deq 0
    }

    if (i + 3 < n) {
        const float4 xv = *reinterpret_cast<const float4*>(x + i);
        float4 ov;
        ov.x = __fmul_rn(qlevel(__fdiv_rn(xv.x, s)), ds);
        ov.y = __fmul_rn(qlevel(__fdiv_rn(xv.y, s)), ds);
        ov.z = __fmul_rn(qlevel(__fdiv_rn(xv.z, s)), ds);
        ov.w = __fmul_rn(qlevel(__fdiv_rn(xv.w, s)), ds);
        *reinterpret_cast<float4*>(out + i) = ov;
    } else {
        for (int j = 0; j < 4 && i + j < n; ++j)
            out[i + j] = __fmul_rn(qlevel(__fdiv_rn(x[i + j], s)), ds);
    }
}

extern "C" void kernel_launch(void* const* d_in, const int* in_sizes, int n_in,
                              void* d_out, int out_size, void* d_ws, size_t ws_size,
                              hipStream_t stream) {
    const float* x = (const float*)d_in[0];
    float* out = (float*)d_out;
    const int n = in_sizes[0];
    const int nblocks = (n + BLK - 1) / BLK;          // 262144 for n=16.7M
    const int nwgA = (nblocks + WG - 1) / WG;         // 1024

    float* ws = (float*)d_ws;
    float* scales = ws;                                // nblocks floats
    unsigned int* hdr = (unsigned int*)(ws + nblocks); // 2 uints (min, max bits)

    // Header init: 0xFFFFFFFF = uint-max (min slot), 0x0 (max slot).
    // Stream-ordered 4-byte memsets; graph-capturable.
    (void)hipMemsetAsync(hdr, 0xFF, 4, stream);
    (void)hipMemsetAsync(hdr + 1, 0x00, 4, stream);

    k_scales<<<nwgA, WG, 0, stream>>>(x, n, nblocks, scales, hdr);
    k_quant<<<((n + 3) / 4 + WG - 1) / WG, WG, 0, stream>>>(x, scales, hdr, n, out);
}

// Round 6
// 137.191 us; speedup vs baseline: 1.0416x; 1.0416x over previous
//
#include <hip/hip_runtime.h>
#include <stdint.h>

// FP4 quant-dequant, faithful to the JAX reference in float32 arithmetic.
// v8: coalescing fix for k_scales. Post-mortem chain: v5/v7 showed ~7us per
// extra dispatch and 4x transaction amplification for fat-thread layouts.
// k_scales' old one-thread-per-block layout (256-B lane stride) was request-
// rate-bound at ~35-40us for 67 MB. v8 uses 8 lanes per 64-block: lane l
// loads float4 l and l+8 -> every 64-B line covered by 4 consecutive lanes
// (fully coalesced), then exact top-5 shfl_xor merge across the 8 lanes
// (order-independent exact multiset top-5; same pattern as the v3/v4 phase-1
// which passed bit-identically). k_quant keeps v2-verbatim math (4 elems/
// thread, 16-B lane stride) + inline 1-entry-per-thread smin/smax reduce of
// <=1024 WG partials (deterministic -> bit-identical everywhere).
// 2 dispatches total, no memsets, no atomics.

#define BLK 64
#define WGS 1024          // workgroup size for both kernels (16 waves)
#define GRID_SCALES 1024  // max k_scales WGs; also partial-array bound
#define FLT_BIG 3.402823466e+38f

// Branchless insert of `a` into descending-sorted top-5 register array.
__device__ __forceinline__ void ins5(float (&t)[5], float a) {
#pragma unroll
    for (int k = 0; k < 4; ++k) {
        float m = fmaxf(t[k], a);
        a = fminf(t[k], a);
        t[k] = m;
    }
    t[4] = fmaxf(t[4], a);
}

// JAX f32 quantile: q = 0.95f*63.0f; result = v59*lw + v60*hw
__device__ __forceinline__ float quantile5(const float (&A)[5]) {
    const float qs = 0.95f * 63.0f;      // 59.849998474121094f
    const float hw = qs - 59.0f;
    const float lw = 60.0f - qs;
    // A[3] = 4th largest = sorted v[60]; A[4] = 5th largest = v[59]
    float s = __fadd_rn(__fmul_rn(A[4], lw), __fmul_rn(A[3], hw));
    return fmaxf(s, 1e-8f);
}

// Nearest FP4 level via boundary ladder on the EXACT quotient fl(x/s).
// Midpoints and partial sums are exact dyadics; ties at exact midpoints go
// to the lower-index (more negative) level, matching argmin-first-index.
__device__ __forceinline__ float qlevel(float xn) {
    float bv = -3.0f;
    bv += (xn > -2.5f)   ? 1.0f  : 0.0f;
    bv += (xn > -1.75f)  ? 0.5f  : 0.0f;
    bv += (xn > -1.25f)  ? 0.5f  : 0.0f;
    bv += (xn > -0.875f) ? 0.25f : 0.0f;
    bv += (xn > -0.375f) ? 0.75f : 0.0f;
    bv += (xn > 0.375f)  ? 0.75f : 0.0f;
    bv += (xn > 0.875f)  ? 0.25f : 0.0f;
    bv += (xn > 1.25f)   ? 0.5f  : 0.0f;
    bv += (xn > 1.75f)   ? 0.5f  : 0.0f;
    bv += (xn > 2.5f)    ? 1.0f  : 0.0f;
    return bv;
}

// ---------------- Kernel 1: per-block scales, coalesced ----------------
// 8 lanes own one 64-elem block. Lane l loads float4 #l and #(l+8) of the
// block: 4 consecutive lanes fully cover each 64-B line (coalesced). Exact
// top-5 via per-lane ins5 then 3-step shfl_xor merge (offsets 1,2,4 stay
// inside the 8-lane group). All 8 lanes end with the identical exact top-5.
__global__ __launch_bounds__(WGS) void k_scales(const float* __restrict__ x,
                                                int n, int nblocks,
                                                float* __restrict__ scales,
                                                float* __restrict__ partMin,
                                                float* __restrict__ partMax) {
    const int tid = (int)threadIdx.x;
    const int lanein = tid & 7;
    const int g0 = ((int)blockIdx.x * WGS + tid) >> 3;   // first block
    const int gstep = ((int)gridDim.x * WGS) >> 3;       // blocks per pass

    float mn = FLT_BIG, mx = 0.0f;

    for (int b = g0; b < nblocks; b += gstep) {
        const int base = b * BLK;
        float4 v0, v1;
        if (base + BLK <= n) {
            const float4* x4 = reinterpret_cast<const float4*>(x + base);
            v0 = x4[lanein];
            v1 = x4[lanein + 8];
        } else {
            const int i0 = base + lanein * 4;
            const int i1 = i0 + 32;
            v0.x = (i0 + 0 < n) ? x[i0 + 0] : 0.0f;   // reference zero-pads
            v0.y = (i0 + 1 < n) ? x[i0 + 1] : 0.0f;
            v0.z = (i0 + 2 < n) ? x[i0 + 2] : 0.0f;
            v0.w = (i0 + 3 < n) ? x[i0 + 3] : 0.0f;
            v1.x = (i1 + 0 < n) ? x[i1 + 0] : 0.0f;
            v1.y = (i1 + 1 < n) ? x[i1 + 1] : 0.0f;
            v1.z = (i1 + 2 < n) ? x[i1 + 2] : 0.0f;
            v1.w = (i1 + 3 < n) ? x[i1 + 3] : 0.0f;
        }
        // Per-lane exact top-5 of its 8 |x| (abs>=0 so 0-init is safe).
        float A[5] = {0.f, 0.f, 0.f, 0.f, 0.f};
        ins5(A, fabsf(v0.x)); ins5(A, fabsf(v0.y));
        ins5(A, fabsf(v0.z)); ins5(A, fabsf(v0.w));
        ins5(A, fabsf(v1.x)); ins5(A, fabsf(v1.y));
        ins5(A, fabsf(v1.z)); ins5(A, fabsf(v1.w));
        // Merge across the 8-lane group: after 3 steps every lane holds the
        // exact top-5 of the block's 64 elements (order-independent).
#pragma unroll
        for (int m = 1; m <= 4; m <<= 1) {
            float o0 = __shfl_xor(A[0], m, 64);
            float o1 = __shfl_xor(A[1], m, 64);
            float o2 = __shfl_xor(A[2], m, 64);
            float o3 = __shfl_xor(A[3], m, 64);
            float o4 = __shfl_xor(A[4], m, 64);
            ins5(A, o0); ins5(A, o1); ins5(A, o2); ins5(A, o3); ins5(A, o4);
        }
        const float s = quantile5(A);
        if (lanein == 0) scales[b] = s;
        mn = fminf(mn, s);   // identical s on all 8 lanes: idempotent
        mx = fmaxf(mx, s);
    }

    // Per-WG min/max partial: wave shfl + LDS across 16 waves.
#pragma unroll
    for (int off = 32; off > 0; off >>= 1) {
        mn = fminf(mn, __shfl_xor(mn, off, 64));
        mx = fmaxf(mx, __shfl_xor(mx, off, 64));
    }
    __shared__ float smn[16], smx[16];
    const int lane = tid & 63, w = tid >> 6;
    if (lane == 0) { smn[w] = mn; smx[w] = mx; }
    __syncthreads();
    if (tid == 0) {
        float fmn = smn[0], fmx = smx[0];
#pragma unroll
        for (int i = 1; i < 16; ++i) { fmn = fminf(fmn, smn[i]); fmx = fmaxf(fmx, smx[i]); }
        partMin[blockIdx.x] = fmn;
        partMax[blockIdx.x] = fmx;
    }
}

// ------- Kernel 2: inline smin/smax reduce + quantize (v2-verbatim) -------
// nparts <= 1024 = WGS: each thread reads at most ONE partial pair (2 KB/WG,
// coalesced), then wave shfl + LDS reduce. Deterministic & exact -> same
// smin/smax bits in every WG. Quantize math is byte-identical to verified v2.
__global__ __launch_bounds__(WGS) void k_quant(const float* __restrict__ x,
                                               const float* __restrict__ scales,
                                               const float* __restrict__ partMin,
                                               const float* __restrict__ partMax,
                                               int nparts, int n,
                                               float* __restrict__ out) {
    const int tid = (int)threadIdx.x;
    float mn = (tid < nparts) ? partMin[tid] : FLT_BIG;
    float mx = (tid < nparts) ? partMax[tid] : 0.0f;
#pragma unroll
    for (int off = 32; off > 0; off >>= 1) {
        mn = fminf(mn, __shfl_xor(mn, off, 64));
        mx = fmaxf(mx, __shfl_xor(mx, off, 64));
    }
    __shared__ float smn[16], smx[16];
    const int lane = tid & 63, w = tid >> 6;
    if (lane == 0) { smn[w] = mn; smx[w] = mx; }
    __syncthreads();
    float smin = smn[0], smax = smx[0];
#pragma unroll
    for (int i = 1; i < 16; ++i) { smin = fminf(smin, smn[i]); smax = fmaxf(smax, smx[i]); }

    const int t = (int)blockIdx.x * WGS + tid;
    const int i = t * 4;
    if (i >= n) return;

    const float s = scales[i >> 6];     // 4-aligned group never crosses a block

    // Double-quantization of the scale (exact path).
    float ds;
    if (smax > smin) {
        const float ss = __fdiv_rn(__fsub_rn(smax, smin), 255.0f);
        float q = rintf(__fdiv_rn(__fsub_rn(s, smin), ss));   // round half-even
        q = fminf(fmaxf(q, 0.0f), 255.0f);                    // clip AFTER round
        ds = __fmul_rn(q, ss);
    } else {
        ds = 0.0f;   // q=0, scale_scale=1 -> deq 0
    }

    if (i + 3 < n) {
        const float4 xv = *reinterpret_cast<const float4*>(x + i);
        float4 ov;
        ov.x = __fmul_rn(qlevel(__fdiv_rn(xv.x, s)), ds);
        ov.y = __fmul_rn(qlevel(__fdiv_rn(xv.y, s)), ds);
        ov.z = __fmul_rn(qlevel(__fdiv_rn(xv.z, s)), ds);
        ov.w = __fmul_rn(qlevel(__fdiv_rn(xv.w, s)), ds);
        *reinterpret_cast<float4*>(out + i) = ov;
    } else {
        for (int j = 0; j < 4 && i + j < n; ++j)
            out[i + j] = __fmul_rn(qlevel(__fdiv_rn(x[i + j], s)), ds);
    }
}

extern "C" void kernel_launch(void* const* d_in, const int* in_sizes, int n_in,
                              void* d_out, int out_size, void* d_ws, size_t ws_size,
                              hipStream_t stream) {
    const float* x = (const float*)d_in[0];
    float* out = (float*)d_out;
    const int n = in_sizes[0];
    const int nblocks = (n + BLK - 1) / BLK;           // 262144 for n=16.7M

    // k_scales grid: 128 blocks per WG-pass (1024 thr / 8 lanes-per-block).
    int nwgS = (nblocks + 127) / 128;
    if (nwgS > GRID_SCALES) nwgS = GRID_SCALES;
    if (nwgS < 1) nwgS = 1;
    const int nwgQ = (int)(((long long)n / 4 + WGS) / WGS) + 1;  // covers tail

    float* ws = (float*)d_ws;
    float* scales  = ws;                     // nblocks floats
    float* partMin = ws + nblocks;           // GRID_SCALES floats
    float* partMax = partMin + GRID_SCALES;  // GRID_SCALES floats

    k_scales<<<nwgS, WGS, 0, stream>>>(x, n, nblocks, scales, partMin, partMax);
    k_quant<<<nwgQ, WGS, 0, stream>>>(x, scales, partMin, partMax, nwgS, n, out);
}